// Round 17
// baseline (237.092 us; speedup 1.0000x reference)
//
#include <hip/hip_runtime.h>

// VQ codebook via MFMA: z_e (262144,64) f32, embeddings (512,64) f32.
// Outputs (flat f32): z_q_st [N*D], indices-as-float [N], loss [1].
//
// R17 = R16 with the register budget pinned back to the 8-block regime:
// __launch_bounds__(256,8) -> VGPR cap 64 (hot loop measured 52 in R14);
// rescan made register-light (#pragma unroll 1: one z4 + one e4 in flight)
// so it fits the cap. R16 post-mortem: inline rescan inflated VGPR 52->88,
// occupancy 35->16%, hot loop 108->148us -- the fusion was right, the
// allocation was wrong. Rescan arithmetic order bitwise = R16 (absmax 0).

typedef short  bf16x8 __attribute__((ext_vector_type(8)));
typedef float  f32x4  __attribute__((ext_vector_type(4)));

static constexpr int N_TOK = 262144;
static constexpr int K     = 512;
static constexpr int D     = 64;
static constexpr float THRESH = 0.02f;
static constexpr int NBLK_A = N_TOK / 128;    // 2048 vq_mfma blocks

// ws layout (bytes)
static constexpr size_t WS_ESQ   = 0;         //  512 f32 (2048 B)
static constexpr size_t WS_BL    = 2048;      // 2048 f32 (8192 B)
static constexpr size_t WS_EFRAG = 10240;     // 65536 u16 (131072 B), 16B-al

#define GLDS16(G, L) __builtin_amdgcn_global_load_lds(                    \
    (const __attribute__((address_space(1))) void*)(G),                   \
    (__attribute__((address_space(3))) void*)(L), 16, 0, 0)

// ---- prep: E' = -2E -> bf16 hi/lo A-frags, fused with esq ------------------
__global__ __launch_bounds__(512) void prep_kernel(
    const float* __restrict__ emb, unsigned short* __restrict__ ef,
    float* __restrict__ esq) {
  int idx  = blockIdx.x * 512 + threadIdx.x;   // 32768 = 512 codes * 64 d
  int code = idx >> 6, d = idx & 63;
  float s  = -2.0f * emb[code * 64 + d];
  unsigned u  = __float_as_uint(s);
  unsigned hi = (u + 0x7FFFu + ((u >> 16) & 1u)) >> 16;       // RNE bf16
  float lof   = s - __uint_as_float(hi << 16);
  unsigned v2 = __float_as_uint(lof);
  unsigned lo = (v2 + 0x7FFFu + ((v2 >> 16) & 1u)) >> 16;     // RNE bf16
  int tile = code >> 4, row = code & 15;
  int c = (d >> 5) & 1, g = (d >> 3) & 3, i = d & 7;
  int lane = row + (g << 4);
  size_t base = ((size_t)tile * 256 + (size_t)c * 128) * 8;
  ef[base + (size_t)(0 * 64 + lane) * 8 + i] = (unsigned short)hi;
  ef[base + (size_t)(1 * 64 + lane) * 8 + i] = (unsigned short)lo;
  // esq for this block's 8 codes (rows L1-hot from the reads above).
  if (threadIdx.x < 8) {
    int k = blockIdx.x * 8 + threadIdx.x;
    const float4* row4 = reinterpret_cast<const float4*>(emb + (size_t)k * D);
    float acc = 0.f;
#pragma unroll
    for (int j = 0; j < 16; ++j) {
      float4 v = row4[j];
      acc = fmaf(v.x, v.x, acc); acc = fmaf(v.y, v.y, acc);
      acc = fmaf(v.z, v.z, acc); acc = fmaf(v.w, v.w, acc);
    }
    esq[k] = acc;
  }
}

// RNE bf16 two-term split of 8 floats -> hi/lo bf16x8.
__device__ __forceinline__ void split8(float4 a, float4 b,
                                       bf16x8& h, bf16x8& lo) {
  float v[8] = {a.x, a.y, a.z, a.w, b.x, b.y, b.z, b.w};
#pragma unroll
  for (int i = 0; i < 8; ++i) {
    unsigned u  = __float_as_uint(v[i]);
    unsigned hi = (u + 0x7FFFu + ((u >> 16) & 1u)) >> 16;
    float lof   = v[i] - __uint_as_float(hi << 16);
    unsigned v2 = __float_as_uint(lof);
    unsigned l2 = (v2 + 0x7FFFu + ((v2 >> 16) & 1u)) >> 16;
    h[i]  = (short)hi;
    lo[i] = (short)l2;
  }
}

#define ARGMIN4(C, BASE, BEST, SECOND, BIDXV)               \
  {                                                         \
    _Pragma("unroll")                                       \
    for (int r = 0; r < 4; ++r) {                           \
      float v = (C)[r];                                     \
      bool lt = v < (BEST);                                 \
      float mn = fminf((SECOND), v);                        \
      (SECOND) = lt ? (BEST) : mn;                          \
      (BIDXV)  = lt ? ((BASE) + r) : (BIDXV);               \
      (BEST)   = lt ? v : (BEST);                           \
    }                                                       \
  }

// ---- kernel A: MFMA distances + inline rescan + fused epilogue -------------
__global__ __launch_bounds__(256, 8) void vq_mfma(
    const float* __restrict__ z_e, const float* __restrict__ emb,
    const unsigned short* __restrict__ efrag, const float* __restrict__ esq_g,
    float* __restrict__ out_zq, float* __restrict__ out_idx,
    float* __restrict__ block_loss) {
  __shared__ float esql[K];                        // 2048 B
  __shared__ __align__(16) short lds_eb[2][4096];  // 2 x 8KB (tile-pair dbuf)
  __shared__ int   sIdx[128];
  __shared__ float wsm[4];

  const int t  = threadIdx.x;
  const int l  = t & 63;
  const int w  = t >> 6;
  const int wu = __builtin_amdgcn_readfirstlane(w);  // SGPR wave id
  const int g  = l >> 4, g4 = g << 2;
  const int gtok0 = blockIdx.x * 128;

  esql[t] = esq_g[t];
  esql[t + 256] = esq_g[t + 256];

  // z frags for two token rows, direct from global. RNE split = efrag's.
  bf16x8 zh0A, zl0A, zh1A, zl1A, zh0B, zl0B, zh1B, zl1B;
  {
    const int rowA = gtok0 + w * 32 + (l & 15);
    const float* zp = z_e + (size_t)rowA * D + g * 8;
    float4 q0 = *reinterpret_cast<const float4*>(zp);
    float4 q1 = *reinterpret_cast<const float4*>(zp + 4);
    float4 q2 = *reinterpret_cast<const float4*>(zp + 32);
    float4 q3 = *reinterpret_cast<const float4*>(zp + 36);
    split8(q0, q1, zh0A, zl0A);
    split8(q2, q3, zh1A, zl1A);
    zp += (size_t)16 * D;                          // rowB = rowA + 16
    q0 = *reinterpret_cast<const float4*>(zp);
    q1 = *reinterpret_cast<const float4*>(zp + 4);
    q2 = *reinterpret_cast<const float4*>(zp + 32);
    q3 = *reinterpret_cast<const float4*>(zp + 36);
    split8(q0, q1, zh0B, zl0B);
    split8(q2, q3, zh1B, zl1B);
  }

  const bf16x8* EF = reinterpret_cast<const bf16x8*>(efrag);
  GLDS16(EF + t,       &lds_eb[0][wu * 512]);
  GLDS16(EF + 256 + t, &lds_eb[0][2048 + wu * 512]);
  __syncthreads();

  float bestA = 3.402823466e38f, secondA = 3.402823466e38f;
  float bestB = 3.402823466e38f, secondB = 3.402823466e38f;
  int idxA = 0, idxB = 0;
  int buf = 0;

  for (int it = 0; it < 16; ++it) {
    if (it < 15) {                                 // stage next pair early
      const bf16x8* src = EF + (size_t)(it + 1) * 512;
      GLDS16(src + t,       &lds_eb[buf ^ 1][wu * 512]);
      GLDS16(src + 256 + t, &lds_eb[buf ^ 1][2048 + wu * 512]);
    }
    const bf16x8* eb = reinterpret_cast<const bf16x8*>(&lds_eb[buf][0]);

#pragma unroll
    for (int half = 0; half < 2; ++half) {
      const int tile = 2 * it + half;
      const bf16x8* tb = eb + half * 256;
      f32x4 CA = *reinterpret_cast<const f32x4*>(&esql[tile * 16 + g4]);
      f32x4 CB = CA;
      bf16x8 e0h = tb[l], e0l = tb[64 + l];
      bf16x8 e1h = tb[128 + l], e1l = tb[192 + l];
      __builtin_amdgcn_s_setprio(1);
      CA = __builtin_amdgcn_mfma_f32_16x16x32_bf16(e0h, zh0A, CA, 0, 0, 0);
      CB = __builtin_amdgcn_mfma_f32_16x16x32_bf16(e0h, zh0B, CB, 0, 0, 0);
      CA = __builtin_amdgcn_mfma_f32_16x16x32_bf16(e0h, zl0A, CA, 0, 0, 0);
      CB = __builtin_amdgcn_mfma_f32_16x16x32_bf16(e0h, zl0B, CB, 0, 0, 0);
      CA = __builtin_amdgcn_mfma_f32_16x16x32_bf16(e0l, zh0A, CA, 0, 0, 0);
      CB = __builtin_amdgcn_mfma_f32_16x16x32_bf16(e0l, zh0B, CB, 0, 0, 0);
      CA = __builtin_amdgcn_mfma_f32_16x16x32_bf16(e1h, zh1A, CA, 0, 0, 0);
      CB = __builtin_amdgcn_mfma_f32_16x16x32_bf16(e1h, zh1B, CB, 0, 0, 0);
      CA = __builtin_amdgcn_mfma_f32_16x16x32_bf16(e1h, zl1A, CA, 0, 0, 0);
      CB = __builtin_amdgcn_mfma_f32_16x16x32_bf16(e1h, zl1B, CB, 0, 0, 0);
      CA = __builtin_amdgcn_mfma_f32_16x16x32_bf16(e1l, zh1A, CA, 0, 0, 0);
      CB = __builtin_amdgcn_mfma_f32_16x16x32_bf16(e1l, zh1B, CB, 0, 0, 0);
      __builtin_amdgcn_s_setprio(0);

      const int base = tile * 16 + g4;             // ascending code order
      ARGMIN4(CA, base, bestA, secondA, idxA)
      ARGMIN4(CB, base, bestB, secondB, idxB)
    }
    __syncthreads();
    buf ^= 1;
  }

  // Reduce each group across lanes {l, l^16, l^32, l^48}; ties -> smaller code.
#pragma unroll
  for (int mask = 16; mask <= 32; mask <<= 1) {
    float ob, os; int oi; bool take; float hi2;
    ob = __shfl_xor(bestA, mask); oi = __shfl_xor(idxA, mask);
    os = __shfl_xor(secondA, mask);
    hi2 = fmaxf(bestA, ob);
    secondA = fminf(secondA, fminf(os, hi2));
    take = (ob < bestA) || (ob == bestA && oi < idxA);
    bestA = take ? ob : bestA; idxA = take ? oi : idxA;

    ob = __shfl_xor(bestB, mask); oi = __shfl_xor(idxB, mask);
    os = __shfl_xor(secondB, mask);
    hi2 = fmaxf(bestB, ob);
    secondB = fminf(secondB, fminf(os, hi2));
    take = (ob < bestB) || (ob == bestB && oi < idxB);
    bestB = take ? ob : bestB; idxB = take ? oi : idxB;
  }

  if (l < 16) {
    sIdx[w * 32 + l]      = idxA;
    sIdx[w * 32 + 16 + l] = idxB;
  }

  // Inline exact rescan of flagged tokens (wave-uniform ballot loop).
  // Register-light: unroll 1 -> one z4 + one e4 in flight under the 64 cap.
  {
    bool fA = (l < 16) && ((secondA - bestA) < THRESH);
    bool fB = (l < 16) && ((secondB - bestB) < THRESH);
    unsigned long long ba = __ballot(fA);
    unsigned long long bb = __ballot(fB);
    unsigned mask = (unsigned)((ba & 0xFFFFull) | ((bb & 0xFFFFull) << 16));
    while (mask) {
      const int j = __builtin_ctz(mask);
      mask &= mask - 1;
      const int n = gtok0 + w * 32 + j;
      const float4* zr = reinterpret_cast<const float4*>(z_e + (size_t)n * D);
      float acc[8];
#pragma unroll
      for (int m = 0; m < 8; ++m) acc[m] = 0.f;
#pragma unroll 1
      for (int i = 0; i < 16; ++i) {
        float4 z4 = zr[i];                         // uniform addr broadcast
#pragma unroll
        for (int m = 0; m < 8; ++m) {
          const float4 e4 = *reinterpret_cast<const float4*>(
              emb + (size_t)(l + 64 * m) * D + 4 * i);
          acc[m] = fmaf(z4.x, e4.x, acc[m]);
          acc[m] = fmaf(z4.y, e4.y, acc[m]);
          acc[m] = fmaf(z4.z, e4.z, acc[m]);
          acc[m] = fmaf(z4.w, e4.w, acc[m]);
        }
      }
      float best = 3.402823466e38f; int bid = 0;
#pragma unroll
      for (int m = 0; m < 8; ++m) {
        float s = fmaf(-2.f, acc[m], esq_g[l + 64 * m]);
        if (s < best) { best = s; bid = l + 64 * m; }
      }
#pragma unroll
      for (int mk = 1; mk <= 32; mk <<= 1) {       // lexicographic min
        float ob = __shfl_xor(best, mk);
        int   oi = __shfl_xor(bid, mk);
        bool take = (ob < best) || (ob == best && oi < bid);
        best = take ? ob : best;
        bid  = take ? oi : bid;
      }
      if (l == 0) sIdx[w * 32 + j] = bid;          // patch before epilogue
    }
  }
  __syncthreads();

  // Fused epilogue: 2 threads/token; gather + z_q_st + idx + loss.
  {
    const int tk = t >> 1, h = t & 1;
    const int n = gtok0 + tk;
    const int bi = sIdx[tk];
    const float4* er = reinterpret_cast<const float4*>(emb + (size_t)bi * D);
    const float4* zr = reinterpret_cast<const float4*>(z_e + (size_t)n * D);
    float4* orow = reinterpret_cast<float4*>(out_zq + (size_t)n * D);
    float lsum = 0.f;
#pragma unroll
    for (int j = 0; j < 8; ++j) {
      int i = h * 8 + j;
      float4 Q = er[i], Z = zr[i];
      float dx = Q.x - Z.x, dy = Q.y - Z.y, dz = Q.z - Z.z, dw = Q.w - Z.w;
      float4 st;
      st.x = Z.x + dx; st.y = Z.y + dy; st.z = Z.z + dz; st.w = Z.w + dw;
      orow[i] = st;
      lsum = fmaf(dx, dx, lsum); lsum = fmaf(dy, dy, lsum);
      lsum = fmaf(dz, dz, lsum); lsum = fmaf(dw, dw, lsum);
    }
    if (h == 0) out_idx[n] = (float)bi;
    float s = lsum;
#pragma unroll
    for (int off = 32; off > 0; off >>= 1) s += __shfl_xor(s, off, 64);
    if (l == 0) wsm[w] = s;
  }
  __syncthreads();
  if (t == 0) block_loss[blockIdx.x] = ((wsm[0] + wsm[1]) + wsm[2]) + wsm[3];
}

// ---- finalize loss (deterministic tree) ------------------------------------
__global__ __launch_bounds__(256) void loss_finalize(
    const float* __restrict__ bl, float* __restrict__ out_loss) {
  __shared__ float sm[256];
  const int t = threadIdx.x;
  float s = 0.f;
  for (int i = t; i < NBLK_A; i += 256) s += bl[i];
  sm[t] = s;
  __syncthreads();
#pragma unroll
  for (int off = 128; off > 0; off >>= 1) {
    if (t < off) sm[t] += sm[t + off];
    __syncthreads();
  }
  if (t == 0) out_loss[0] = sm[0] * (1.0f / 16777216.0f);  // /(N*D)
}

extern "C" void kernel_launch(void* const* d_in, const int* in_sizes, int n_in,
                              void* d_out, int out_size, void* d_ws, size_t ws_size,
                              hipStream_t stream) {
  const float* z_e = (const float*)d_in[0];
  const float* emb = (const float*)d_in[1];

  float* out      = (float*)d_out;
  float* out_zq   = out;                          // N*D
  float* out_idx  = out + (size_t)N_TOK * D;      // N
  float* out_loss = out_idx + N_TOK;              // 1

  char* wsb = (char*)d_ws;
  float*          esqp = (float*)(wsb + WS_ESQ);
  float*          bl   = (float*)(wsb + WS_BL);
  unsigned short* ef   = (unsigned short*)(wsb + WS_EFRAG);

  prep_kernel<<<64, 512, 0, stream>>>(emb, ef, esqp);
  vq_mfma<<<NBLK_A, 256, 0, stream>>>(z_e, emb, ef, esqp, out_zq, out_idx, bl);
  loss_finalize<<<1, 256, 0, stream>>>(bl, out_loss);
}

// Round 18
// 139.329 us; speedup vs baseline: 1.7017x; 1.7017x over previous
//
#include <hip/hip_runtime.h>

// VQ codebook via MFMA: z_e (262144,64) f32, embeddings (512,64) f32.
// Outputs (flat f32): z_q_st [N*D], indices-as-float [N], loss [1].
//
// R18 = R16 (best, 144.8us) with the rescan made register-light IN SOURCE:
// two acc[4] passes + unroll-1 d-loop (live set ~14 regs < hot loop's 52).
// R17 lesson: ANY occupancy attribute (launch_bounds(,8), waves_per_eu)
// makes the allocator pick a pathological budget (32 VGPR -> full spill,
// 308MB scratch fetch). Default allocation + source-level live-set control
// is the only working regime. Selection semantics bitwise = R16 (absmax 0):
// per-code fmaf chains unchanged; ascending-index first-min preserved
// (two-pass lexicographic merge == single ascending scan).

typedef short  bf16x8 __attribute__((ext_vector_type(8)));
typedef float  f32x4  __attribute__((ext_vector_type(4)));

static constexpr int N_TOK = 262144;
static constexpr int K     = 512;
static constexpr int D     = 64;
static constexpr float THRESH = 0.02f;
static constexpr int NBLK_A = N_TOK / 128;    // 2048 vq_mfma blocks

// ws layout (bytes)
static constexpr size_t WS_ESQ   = 0;         //  512 f32 (2048 B)
static constexpr size_t WS_BL    = 2048;      // 2048 f32 (8192 B)
static constexpr size_t WS_EFRAG = 10240;     // 65536 u16 (131072 B), 16B-al

#define GLDS16(G, L) __builtin_amdgcn_global_load_lds(                    \
    (const __attribute__((address_space(1))) void*)(G),                   \
    (__attribute__((address_space(3))) void*)(L), 16, 0, 0)

// ---- prep: E' = -2E -> bf16 hi/lo A-frags, fused with esq ------------------
__global__ __launch_bounds__(512) void prep_kernel(
    const float* __restrict__ emb, unsigned short* __restrict__ ef,
    float* __restrict__ esq) {
  int idx  = blockIdx.x * 512 + threadIdx.x;   // 32768 = 512 codes * 64 d
  int code = idx >> 6, d = idx & 63;
  float s  = -2.0f * emb[code * 64 + d];
  unsigned u  = __float_as_uint(s);
  unsigned hi = (u + 0x7FFFu + ((u >> 16) & 1u)) >> 16;       // RNE bf16
  float lof   = s - __uint_as_float(hi << 16);
  unsigned v2 = __float_as_uint(lof);
  unsigned lo = (v2 + 0x7FFFu + ((v2 >> 16) & 1u)) >> 16;     // RNE bf16
  int tile = code >> 4, row = code & 15;
  int c = (d >> 5) & 1, g = (d >> 3) & 3, i = d & 7;
  int lane = row + (g << 4);
  size_t base = ((size_t)tile * 256 + (size_t)c * 128) * 8;
  ef[base + (size_t)(0 * 64 + lane) * 8 + i] = (unsigned short)hi;
  ef[base + (size_t)(1 * 64 + lane) * 8 + i] = (unsigned short)lo;
  // esq for this block's 8 codes (rows L1-hot from the reads above).
  if (threadIdx.x < 8) {
    int k = blockIdx.x * 8 + threadIdx.x;
    const float4* row4 = reinterpret_cast<const float4*>(emb + (size_t)k * D);
    float acc = 0.f;
#pragma unroll
    for (int j = 0; j < 16; ++j) {
      float4 v = row4[j];
      acc = fmaf(v.x, v.x, acc); acc = fmaf(v.y, v.y, acc);
      acc = fmaf(v.z, v.z, acc); acc = fmaf(v.w, v.w, acc);
    }
    esq[k] = acc;
  }
}

// RNE bf16 two-term split of 8 floats -> hi/lo bf16x8.
__device__ __forceinline__ void split8(float4 a, float4 b,
                                       bf16x8& h, bf16x8& lo) {
  float v[8] = {a.x, a.y, a.z, a.w, b.x, b.y, b.z, b.w};
#pragma unroll
  for (int i = 0; i < 8; ++i) {
    unsigned u  = __float_as_uint(v[i]);
    unsigned hi = (u + 0x7FFFu + ((u >> 16) & 1u)) >> 16;
    float lof   = v[i] - __uint_as_float(hi << 16);
    unsigned v2 = __float_as_uint(lof);
    unsigned l2 = (v2 + 0x7FFFu + ((v2 >> 16) & 1u)) >> 16;
    h[i]  = (short)hi;
    lo[i] = (short)l2;
  }
}

#define ARGMIN4(C, BASE, BEST, SECOND, BIDXV)               \
  {                                                         \
    _Pragma("unroll")                                       \
    for (int r = 0; r < 4; ++r) {                           \
      float v = (C)[r];                                     \
      bool lt = v < (BEST);                                 \
      float mn = fminf((SECOND), v);                        \
      (SECOND) = lt ? (BEST) : mn;                          \
      (BIDXV)  = lt ? ((BASE) + r) : (BIDXV);               \
      (BEST)   = lt ? v : (BEST);                           \
    }                                                       \
  }

// ---- kernel A: MFMA distances + inline rescan + fused epilogue -------------
__global__ __launch_bounds__(256) void vq_mfma(
    const float* __restrict__ z_e, const float* __restrict__ emb,
    const unsigned short* __restrict__ efrag, const float* __restrict__ esq_g,
    float* __restrict__ out_zq, float* __restrict__ out_idx,
    float* __restrict__ block_loss) {
  __shared__ float esql[K];                        // 2048 B
  __shared__ __align__(16) short lds_eb[2][4096];  // 2 x 8KB (tile-pair dbuf)
  __shared__ int   sIdx[128];
  __shared__ float wsm[4];

  const int t  = threadIdx.x;
  const int l  = t & 63;
  const int w  = t >> 6;
  const int wu = __builtin_amdgcn_readfirstlane(w);  // SGPR wave id
  const int g  = l >> 4, g4 = g << 2;
  const int gtok0 = blockIdx.x * 128;

  esql[t] = esq_g[t];
  esql[t + 256] = esq_g[t + 256];

  // z frags for two token rows, direct from global. RNE split = efrag's.
  bf16x8 zh0A, zl0A, zh1A, zl1A, zh0B, zl0B, zh1B, zl1B;
  {
    const int rowA = gtok0 + w * 32 + (l & 15);
    const float* zp = z_e + (size_t)rowA * D + g * 8;
    float4 q0 = *reinterpret_cast<const float4*>(zp);
    float4 q1 = *reinterpret_cast<const float4*>(zp + 4);
    float4 q2 = *reinterpret_cast<const float4*>(zp + 32);
    float4 q3 = *reinterpret_cast<const float4*>(zp + 36);
    split8(q0, q1, zh0A, zl0A);
    split8(q2, q3, zh1A, zl1A);
    zp += (size_t)16 * D;                          // rowB = rowA + 16
    q0 = *reinterpret_cast<const float4*>(zp);
    q1 = *reinterpret_cast<const float4*>(zp + 4);
    q2 = *reinterpret_cast<const float4*>(zp + 32);
    q3 = *reinterpret_cast<const float4*>(zp + 36);
    split8(q0, q1, zh0B, zl0B);
    split8(q2, q3, zh1B, zl1B);
  }

  const bf16x8* EF = reinterpret_cast<const bf16x8*>(efrag);
  GLDS16(EF + t,       &lds_eb[0][wu * 512]);
  GLDS16(EF + 256 + t, &lds_eb[0][2048 + wu * 512]);
  __syncthreads();

  float bestA = 3.402823466e38f, secondA = 3.402823466e38f;
  float bestB = 3.402823466e38f, secondB = 3.402823466e38f;
  int idxA = 0, idxB = 0;
  int buf = 0;

  for (int it = 0; it < 16; ++it) {
    if (it < 15) {                                 // stage next pair early
      const bf16x8* src = EF + (size_t)(it + 1) * 512;
      GLDS16(src + t,       &lds_eb[buf ^ 1][wu * 512]);
      GLDS16(src + 256 + t, &lds_eb[buf ^ 1][2048 + wu * 512]);
    }
    const bf16x8* eb = reinterpret_cast<const bf16x8*>(&lds_eb[buf][0]);

#pragma unroll
    for (int half = 0; half < 2; ++half) {
      const int tile = 2 * it + half;
      const bf16x8* tb = eb + half * 256;
      f32x4 CA = *reinterpret_cast<const f32x4*>(&esql[tile * 16 + g4]);
      f32x4 CB = CA;
      bf16x8 e0h = tb[l], e0l = tb[64 + l];
      bf16x8 e1h = tb[128 + l], e1l = tb[192 + l];
      __builtin_amdgcn_s_setprio(1);
      CA = __builtin_amdgcn_mfma_f32_16x16x32_bf16(e0h, zh0A, CA, 0, 0, 0);
      CB = __builtin_amdgcn_mfma_f32_16x16x32_bf16(e0h, zh0B, CB, 0, 0, 0);
      CA = __builtin_amdgcn_mfma_f32_16x16x32_bf16(e0h, zl0A, CA, 0, 0, 0);
      CB = __builtin_amdgcn_mfma_f32_16x16x32_bf16(e0h, zl0B, CB, 0, 0, 0);
      CA = __builtin_amdgcn_mfma_f32_16x16x32_bf16(e0l, zh0A, CA, 0, 0, 0);
      CB = __builtin_amdgcn_mfma_f32_16x16x32_bf16(e0l, zh0B, CB, 0, 0, 0);
      CA = __builtin_amdgcn_mfma_f32_16x16x32_bf16(e1h, zh1A, CA, 0, 0, 0);
      CB = __builtin_amdgcn_mfma_f32_16x16x32_bf16(e1h, zh1B, CB, 0, 0, 0);
      CA = __builtin_amdgcn_mfma_f32_16x16x32_bf16(e1h, zl1A, CA, 0, 0, 0);
      CB = __builtin_amdgcn_mfma_f32_16x16x32_bf16(e1h, zl1B, CB, 0, 0, 0);
      CA = __builtin_amdgcn_mfma_f32_16x16x32_bf16(e1l, zh1A, CA, 0, 0, 0);
      CB = __builtin_amdgcn_mfma_f32_16x16x32_bf16(e1l, zh1B, CB, 0, 0, 0);
      __builtin_amdgcn_s_setprio(0);

      const int base = tile * 16 + g4;             // ascending code order
      ARGMIN4(CA, base, bestA, secondA, idxA)
      ARGMIN4(CB, base, bestB, secondB, idxB)
    }
    __syncthreads();
    buf ^= 1;
  }

  // Reduce each group across lanes {l, l^16, l^32, l^48}; ties -> smaller code.
#pragma unroll
  for (int mask = 16; mask <= 32; mask <<= 1) {
    float ob, os; int oi; bool take; float hi2;
    ob = __shfl_xor(bestA, mask); oi = __shfl_xor(idxA, mask);
    os = __shfl_xor(secondA, mask);
    hi2 = fmaxf(bestA, ob);
    secondA = fminf(secondA, fminf(os, hi2));
    take = (ob < bestA) || (ob == bestA && oi < idxA);
    bestA = take ? ob : bestA; idxA = take ? oi : idxA;

    ob = __shfl_xor(bestB, mask); oi = __shfl_xor(idxB, mask);
    os = __shfl_xor(secondB, mask);
    hi2 = fmaxf(bestB, ob);
    secondB = fminf(secondB, fminf(os, hi2));
    take = (ob < bestB) || (ob == bestB && oi < idxB);
    bestB = take ? ob : bestB; idxB = take ? oi : idxB;
  }

  if (l < 16) {
    sIdx[w * 32 + l]      = idxA;
    sIdx[w * 32 + 16 + l] = idxB;
  }

  // Inline exact rescan of flagged tokens (wave-uniform ballot loop).
  // Register-light: two acc[4] passes, unroll-1 d-loop (one z4 + 4 e4 in
  // flight). Selection == single ascending acc[8] scan (first-min).
  {
    bool fA = (l < 16) && ((secondA - bestA) < THRESH);
    bool fB = (l < 16) && ((secondB - bestB) < THRESH);
    unsigned long long ba = __ballot(fA);
    unsigned long long bb = __ballot(fB);
    unsigned mask = (unsigned)((ba & 0xFFFFull) | ((bb & 0xFFFFull) << 16));
    while (mask) {
      const int j = __builtin_ctz(mask);
      mask &= mask - 1;
      const int n = gtok0 + w * 32 + j;
      const float4* zr = reinterpret_cast<const float4*>(z_e + (size_t)n * D);
      float best = 3.402823466e38f; int bid = 0;
#pragma unroll 1
      for (int half2 = 0; half2 < 2; ++half2) {
        float acc[4];
#pragma unroll
        for (int m = 0; m < 4; ++m) acc[m] = 0.f;
#pragma unroll 1
        for (int i = 0; i < 16; ++i) {
          float4 z4 = zr[i];                       // uniform addr broadcast
#pragma unroll
          for (int m = 0; m < 4; ++m) {
            const float4 e4 = *reinterpret_cast<const float4*>(
                emb + (size_t)(l + 64 * (half2 * 4 + m)) * D + 4 * i);
            acc[m] = fmaf(z4.x, e4.x, acc[m]);
            acc[m] = fmaf(z4.y, e4.y, acc[m]);
            acc[m] = fmaf(z4.z, e4.z, acc[m]);
            acc[m] = fmaf(z4.w, e4.w, acc[m]);
          }
        }
#pragma unroll
        for (int m = 0; m < 4; ++m) {
          const int code = l + 64 * (half2 * 4 + m);
          float s = fmaf(-2.f, acc[m], esq_g[code]);
          if (s < best) { best = s; bid = code; }  // ascending overall
        }
      }
#pragma unroll
      for (int mk = 1; mk <= 32; mk <<= 1) {       // lexicographic min
        float ob = __shfl_xor(best, mk);
        int   oi = __shfl_xor(bid, mk);
        bool take = (ob < best) || (ob == best && oi < bid);
        best = take ? ob : best;
        bid  = take ? oi : bid;
      }
      if (l == 0) sIdx[w * 32 + j] = bid;          // patch before epilogue
    }
  }
  __syncthreads();

  // Fused epilogue: 2 threads/token; gather + z_q_st + idx + loss.
  {
    const int tk = t >> 1, h = t & 1;
    const int n = gtok0 + tk;
    const int bi = sIdx[tk];
    const float4* er = reinterpret_cast<const float4*>(emb + (size_t)bi * D);
    const float4* zr = reinterpret_cast<const float4*>(z_e + (size_t)n * D);
    float4* orow = reinterpret_cast<float4*>(out_zq + (size_t)n * D);
    float lsum = 0.f;
#pragma unroll
    for (int j = 0; j < 8; ++j) {
      int i = h * 8 + j;
      float4 Q = er[i], Z = zr[i];
      float dx = Q.x - Z.x, dy = Q.y - Z.y, dz = Q.z - Z.z, dw = Q.w - Z.w;
      float4 st;
      st.x = Z.x + dx; st.y = Z.y + dy; st.z = Z.z + dz; st.w = Z.w + dw;
      orow[i] = st;
      lsum = fmaf(dx, dx, lsum); lsum = fmaf(dy, dy, lsum);
      lsum = fmaf(dz, dz, lsum); lsum = fmaf(dw, dw, lsum);
    }
    if (h == 0) out_idx[n] = (float)bi;
    float s = lsum;
#pragma unroll
    for (int off = 32; off > 0; off >>= 1) s += __shfl_xor(s, off, 64);
    if (l == 0) wsm[w] = s;
  }
  __syncthreads();
  if (t == 0) block_loss[blockIdx.x] = ((wsm[0] + wsm[1]) + wsm[2]) + wsm[3];
}

// ---- finalize loss (deterministic tree) ------------------------------------
__global__ __launch_bounds__(256) void loss_finalize(
    const float* __restrict__ bl, float* __restrict__ out_loss) {
  __shared__ float sm[256];
  const int t = threadIdx.x;
  float s = 0.f;
  for (int i = t; i < NBLK_A; i += 256) s += bl[i];
  sm[t] = s;
  __syncthreads();
#pragma unroll
  for (int off = 128; off > 0; off >>= 1) {
    if (t < off) sm[t] += sm[t + off];
    __syncthreads();
  }
  if (t == 0) out_loss[0] = sm[0] * (1.0f / 16777216.0f);  // /(N*D)
}

extern "C" void kernel_launch(void* const* d_in, const int* in_sizes, int n_in,
                              void* d_out, int out_size, void* d_ws, size_t ws_size,
                              hipStream_t stream) {
  const float* z_e = (const float*)d_in[0];
  const float* emb = (const float*)d_in[1];

  float* out      = (float*)d_out;
  float* out_zq   = out;                          // N*D
  float* out_idx  = out + (size_t)N_TOK * D;      // N
  float* out_loss = out_idx + N_TOK;              // 1

  char* wsb = (char*)d_ws;
  float*          esqp = (float*)(wsb + WS_ESQ);
  float*          bl   = (float*)(wsb + WS_BL);
  unsigned short* ef   = (unsigned short*)(wsb + WS_EFRAG);

  prep_kernel<<<64, 512, 0, stream>>>(emb, ef, esqp);
  vq_mfma<<<NBLK_A, 256, 0, stream>>>(z_e, emb, ef, esqp, out_zq, out_idx, bl);
  loss_finalize<<<1, 256, 0, stream>>>(bl, out_loss);
}

// Round 19
// 139.057 us; speedup vs baseline: 1.7050x; 1.0020x over previous
//
#include <hip/hip_runtime.h>

// VQ codebook via MFMA: z_e (262144,64) f32, embeddings (512,64) f32.
// Outputs (flat f32): z_q_st [N*D], indices-as-float [N], loss [1].
//
// R19 = R18 with the hot loop's __syncthreads (implicit vmcnt(0) DRAIN each
// iteration -- the m97 barrier-drain stall) replaced by a counted-vmcnt
// double-buffer: compute -> s_barrier -> issue pair(it+2) into consumed buf
// -> s_waitcnt vmcnt(2) (pair(it+1) landed, fresh pair stays in flight) ->
// s_barrier. Prologue issues pairs 0+1 (2-deep). Loads now span iterations
// (T3/T4 pattern); prefetch latency hides under the next 24 MFMAs.
// Everything else (prep, z frags, MFMA order, argmin, rescan, epilogue)
// byte-identical to R18 (passed, absmax 0, VGPR 52).

typedef short  bf16x8 __attribute__((ext_vector_type(8)));
typedef float  f32x4  __attribute__((ext_vector_type(4)));

static constexpr int N_TOK = 262144;
static constexpr int K     = 512;
static constexpr int D     = 64;
static constexpr float THRESH = 0.02f;
static constexpr int NBLK_A = N_TOK / 128;    // 2048 vq_mfma blocks

// ws layout (bytes)
static constexpr size_t WS_ESQ   = 0;         //  512 f32 (2048 B)
static constexpr size_t WS_BL    = 2048;      // 2048 f32 (8192 B)
static constexpr size_t WS_EFRAG = 10240;     // 65536 u16 (131072 B), 16B-al

#define GLDS16(G, L) __builtin_amdgcn_global_load_lds(                    \
    (const __attribute__((address_space(1))) void*)(G),                   \
    (__attribute__((address_space(3))) void*)(L), 16, 0, 0)

// ---- prep: E' = -2E -> bf16 hi/lo A-frags, fused with esq ------------------
__global__ __launch_bounds__(512) void prep_kernel(
    const float* __restrict__ emb, unsigned short* __restrict__ ef,
    float* __restrict__ esq) {
  int idx  = blockIdx.x * 512 + threadIdx.x;   // 32768 = 512 codes * 64 d
  int code = idx >> 6, d = idx & 63;
  float s  = -2.0f * emb[code * 64 + d];
  unsigned u  = __float_as_uint(s);
  unsigned hi = (u + 0x7FFFu + ((u >> 16) & 1u)) >> 16;       // RNE bf16
  float lof   = s - __uint_as_float(hi << 16);
  unsigned v2 = __float_as_uint(lof);
  unsigned lo = (v2 + 0x7FFFu + ((v2 >> 16) & 1u)) >> 16;     // RNE bf16
  int tile = code >> 4, row = code & 15;
  int c = (d >> 5) & 1, g = (d >> 3) & 3, i = d & 7;
  int lane = row + (g << 4);
  size_t base = ((size_t)tile * 256 + (size_t)c * 128) * 8;
  ef[base + (size_t)(0 * 64 + lane) * 8 + i] = (unsigned short)hi;
  ef[base + (size_t)(1 * 64 + lane) * 8 + i] = (unsigned short)lo;
  // esq for this block's 8 codes (rows L1-hot from the reads above).
  if (threadIdx.x < 8) {
    int k = blockIdx.x * 8 + threadIdx.x;
    const float4* row4 = reinterpret_cast<const float4*>(emb + (size_t)k * D);
    float acc = 0.f;
#pragma unroll
    for (int j = 0; j < 16; ++j) {
      float4 v = row4[j];
      acc = fmaf(v.x, v.x, acc); acc = fmaf(v.y, v.y, acc);
      acc = fmaf(v.z, v.z, acc); acc = fmaf(v.w, v.w, acc);
    }
    esq[k] = acc;
  }
}

// RNE bf16 two-term split of 8 floats -> hi/lo bf16x8.
__device__ __forceinline__ void split8(float4 a, float4 b,
                                       bf16x8& h, bf16x8& lo) {
  float v[8] = {a.x, a.y, a.z, a.w, b.x, b.y, b.z, b.w};
#pragma unroll
  for (int i = 0; i < 8; ++i) {
    unsigned u  = __float_as_uint(v[i]);
    unsigned hi = (u + 0x7FFFu + ((u >> 16) & 1u)) >> 16;
    float lof   = v[i] - __uint_as_float(hi << 16);
    unsigned v2 = __float_as_uint(lof);
    unsigned l2 = (v2 + 0x7FFFu + ((v2 >> 16) & 1u)) >> 16;
    h[i]  = (short)hi;
    lo[i] = (short)l2;
  }
}

#define ARGMIN4(C, BASE, BEST, SECOND, BIDXV)               \
  {                                                         \
    _Pragma("unroll")                                       \
    for (int r = 0; r < 4; ++r) {                           \
      float v = (C)[r];                                     \
      bool lt = v < (BEST);                                 \
      float mn = fminf((SECOND), v);                        \
      (SECOND) = lt ? (BEST) : mn;                          \
      (BIDXV)  = lt ? ((BASE) + r) : (BIDXV);               \
      (BEST)   = lt ? v : (BEST);                           \
    }                                                       \
  }

// ---- kernel A: MFMA distances + inline rescan + fused epilogue -------------
__global__ __launch_bounds__(256) void vq_mfma(
    const float* __restrict__ z_e, const float* __restrict__ emb,
    const unsigned short* __restrict__ efrag, const float* __restrict__ esq_g,
    float* __restrict__ out_zq, float* __restrict__ out_idx,
    float* __restrict__ block_loss) {
  __shared__ float esql[K];                        // 2048 B
  __shared__ __align__(16) short lds_eb[2][4096];  // 2 x 8KB (tile-pair dbuf)
  __shared__ int   sIdx[128];
  __shared__ float wsm[4];

  const int t  = threadIdx.x;
  const int l  = t & 63;
  const int w  = t >> 6;
  const int wu = __builtin_amdgcn_readfirstlane(w);  // SGPR wave id
  const int g  = l >> 4, g4 = g << 2;
  const int gtok0 = blockIdx.x * 128;

  esql[t] = esq_g[t];
  esql[t + 256] = esq_g[t + 256];

  // z frags for two token rows, direct from global. RNE split = efrag's.
  // (All z loads are consumed before the loop; in every legal issue order the
  // compiler's data-dep waits retire them before the prologue vmcnt(2).)
  bf16x8 zh0A, zl0A, zh1A, zl1A, zh0B, zl0B, zh1B, zl1B;
  {
    const int rowA = gtok0 + w * 32 + (l & 15);
    const float* zp = z_e + (size_t)rowA * D + g * 8;
    float4 q0 = *reinterpret_cast<const float4*>(zp);
    float4 q1 = *reinterpret_cast<const float4*>(zp + 4);
    float4 q2 = *reinterpret_cast<const float4*>(zp + 32);
    float4 q3 = *reinterpret_cast<const float4*>(zp + 36);
    split8(q0, q1, zh0A, zl0A);
    split8(q2, q3, zh1A, zl1A);
    zp += (size_t)16 * D;                          // rowB = rowA + 16
    q0 = *reinterpret_cast<const float4*>(zp);
    q1 = *reinterpret_cast<const float4*>(zp + 4);
    q2 = *reinterpret_cast<const float4*>(zp + 32);
    q3 = *reinterpret_cast<const float4*>(zp + 36);
    split8(q0, q1, zh0B, zl0B);
    split8(q2, q3, zh1B, zl1B);
  }

  const bf16x8* EF = reinterpret_cast<const bf16x8*>(efrag);
  // Prologue: 2-deep prefetch (pairs 0 and 1 into buf0/buf1).
  GLDS16(EF + t,        &lds_eb[0][wu * 512]);
  GLDS16(EF + 256 + t,  &lds_eb[0][2048 + wu * 512]);
  GLDS16(EF + 512 + t,  &lds_eb[1][wu * 512]);
  GLDS16(EF + 768 + t,  &lds_eb[1][2048 + wu * 512]);
  asm volatile("s_waitcnt vmcnt(2)" ::: "memory");  // pair0 landed
  __builtin_amdgcn_s_barrier();                     // + esql visible
  __builtin_amdgcn_sched_barrier(0);

  float bestA = 3.402823466e38f, secondA = 3.402823466e38f;
  float bestB = 3.402823466e38f, secondB = 3.402823466e38f;
  int idxA = 0, idxB = 0;

  for (int it = 0; it < 16; ++it) {
    const bf16x8* eb = reinterpret_cast<const bf16x8*>(&lds_eb[it & 1][0]);

#pragma unroll
    for (int half = 0; half < 2; ++half) {
      const int tile = 2 * it + half;
      const bf16x8* tb = eb + half * 256;
      f32x4 CA = *reinterpret_cast<const f32x4*>(&esql[tile * 16 + g4]);
      f32x4 CB = CA;
      bf16x8 e0h = tb[l], e0l = tb[64 + l];
      bf16x8 e1h = tb[128 + l], e1l = tb[192 + l];
      __builtin_amdgcn_s_setprio(1);
      CA = __builtin_amdgcn_mfma_f32_16x16x32_bf16(e0h, zh0A, CA, 0, 0, 0);
      CB = __builtin_amdgcn_mfma_f32_16x16x32_bf16(e0h, zh0B, CB, 0, 0, 0);
      CA = __builtin_amdgcn_mfma_f32_16x16x32_bf16(e0h, zl0A, CA, 0, 0, 0);
      CB = __builtin_amdgcn_mfma_f32_16x16x32_bf16(e0h, zl0B, CB, 0, 0, 0);
      CA = __builtin_amdgcn_mfma_f32_16x16x32_bf16(e0l, zh0A, CA, 0, 0, 0);
      CB = __builtin_amdgcn_mfma_f32_16x16x32_bf16(e0l, zh0B, CB, 0, 0, 0);
      CA = __builtin_amdgcn_mfma_f32_16x16x32_bf16(e1h, zh1A, CA, 0, 0, 0);
      CB = __builtin_amdgcn_mfma_f32_16x16x32_bf16(e1h, zh1B, CB, 0, 0, 0);
      CA = __builtin_amdgcn_mfma_f32_16x16x32_bf16(e1h, zl1A, CA, 0, 0, 0);
      CB = __builtin_amdgcn_mfma_f32_16x16x32_bf16(e1h, zl1B, CB, 0, 0, 0);
      CA = __builtin_amdgcn_mfma_f32_16x16x32_bf16(e1l, zh1A, CA, 0, 0, 0);
      CB = __builtin_amdgcn_mfma_f32_16x16x32_bf16(e1l, zh1B, CB, 0, 0, 0);
      __builtin_amdgcn_s_setprio(0);

      const int base = tile * 16 + g4;             // ascending code order
      ARGMIN4(CA, base, bestA, secondA, idxA)
      ARGMIN4(CB, base, bestB, secondB, idxB)
    }

    // Counted-vmcnt buffer rotation (no full drain in steady state).
    __builtin_amdgcn_sched_barrier(0);
    __builtin_amdgcn_s_barrier();                  // all waves done reading buf
    if (it < 14) {
      const bf16x8* src = EF + (size_t)(it + 2) * 512;
      GLDS16(src + t,       &lds_eb[it & 1][wu * 512]);        // reuse buf
      GLDS16(src + 256 + t, &lds_eb[it & 1][2048 + wu * 512]);
      asm volatile("s_waitcnt vmcnt(2)" ::: "memory");  // pair(it+1) landed
    } else if (it == 14) {
      asm volatile("s_waitcnt vmcnt(0)" ::: "memory");  // pair15 landed
    }
    __builtin_amdgcn_s_barrier();                  // landed for ALL waves
    __builtin_amdgcn_sched_barrier(0);
  }

  // Reduce each group across lanes {l, l^16, l^32, l^48}; ties -> smaller code.
#pragma unroll
  for (int mask = 16; mask <= 32; mask <<= 1) {
    float ob, os; int oi; bool take; float hi2;
    ob = __shfl_xor(bestA, mask); oi = __shfl_xor(idxA, mask);
    os = __shfl_xor(secondA, mask);
    hi2 = fmaxf(bestA, ob);
    secondA = fminf(secondA, fminf(os, hi2));
    take = (ob < bestA) || (ob == bestA && oi < idxA);
    bestA = take ? ob : bestA; idxA = take ? oi : idxA;

    ob = __shfl_xor(bestB, mask); oi = __shfl_xor(idxB, mask);
    os = __shfl_xor(secondB, mask);
    hi2 = fmaxf(bestB, ob);
    secondB = fminf(secondB, fminf(os, hi2));
    take = (ob < bestB) || (ob == bestB && oi < idxB);
    bestB = take ? ob : bestB; idxB = take ? oi : idxB;
  }

  if (l < 16) {
    sIdx[w * 32 + l]      = idxA;
    sIdx[w * 32 + 16 + l] = idxB;
  }

  // Inline exact rescan of flagged tokens (wave-uniform ballot loop).
  // Register-light: two acc[4] passes, unroll-1 d-loop.
  {
    bool fA = (l < 16) && ((secondA - bestA) < THRESH);
    bool fB = (l < 16) && ((secondB - bestB) < THRESH);
    unsigned long long ba = __ballot(fA);
    unsigned long long bb = __ballot(fB);
    unsigned mask = (unsigned)((ba & 0xFFFFull) | ((bb & 0xFFFFull) << 16));
    while (mask) {
      const int j = __builtin_ctz(mask);
      mask &= mask - 1;
      const int n = gtok0 + w * 32 + j;
      const float4* zr = reinterpret_cast<const float4*>(z_e + (size_t)n * D);
      float best = 3.402823466e38f; int bid = 0;
#pragma unroll 1
      for (int half2 = 0; half2 < 2; ++half2) {
        float acc[4];
#pragma unroll
        for (int m = 0; m < 4; ++m) acc[m] = 0.f;
#pragma unroll 1
        for (int i = 0; i < 16; ++i) {
          float4 z4 = zr[i];                       // uniform addr broadcast
#pragma unroll
          for (int m = 0; m < 4; ++m) {
            const float4 e4 = *reinterpret_cast<const float4*>(
                emb + (size_t)(l + 64 * (half2 * 4 + m)) * D + 4 * i);
            acc[m] = fmaf(z4.x, e4.x, acc[m]);
            acc[m] = fmaf(z4.y, e4.y, acc[m]);
            acc[m] = fmaf(z4.z, e4.z, acc[m]);
            acc[m] = fmaf(z4.w, e4.w, acc[m]);
          }
        }
#pragma unroll
        for (int m = 0; m < 4; ++m) {
          const int code = l + 64 * (half2 * 4 + m);
          float s = fmaf(-2.f, acc[m], esq_g[code]);
          if (s < best) { best = s; bid = code; }  // ascending overall
        }
      }
#pragma unroll
      for (int mk = 1; mk <= 32; mk <<= 1) {       // lexicographic min
        float ob = __shfl_xor(best, mk);
        int   oi = __shfl_xor(bid, mk);
        bool take = (ob < best) || (ob == best && oi < bid);
        best = take ? ob : best;
        bid  = take ? oi : bid;
      }
      if (l == 0) sIdx[w * 32 + j] = bid;          // patch before epilogue
    }
  }
  __syncthreads();

  // Fused epilogue: 2 threads/token; gather + z_q_st + idx + loss.
  {
    const int tk = t >> 1, h = t & 1;
    const int n = gtok0 + tk;
    const int bi = sIdx[tk];
    const float4* er = reinterpret_cast<const float4*>(emb + (size_t)bi * D);
    const float4* zr = reinterpret_cast<const float4*>(z_e + (size_t)n * D);
    float4* orow = reinterpret_cast<float4*>(out_zq + (size_t)n * D);
    float lsum = 0.f;
#pragma unroll
    for (int j = 0; j < 8; ++j) {
      int i = h * 8 + j;
      float4 Q = er[i], Z = zr[i];
      float dx = Q.x - Z.x, dy = Q.y - Z.y, dz = Q.z - Z.z, dw = Q.w - Z.w;
      float4 st;
      st.x = Z.x + dx; st.y = Z.y + dy; st.z = Z.z + dz; st.w = Z.w + dw;
      orow[i] = st;
      lsum = fmaf(dx, dx, lsum); lsum = fmaf(dy, dy, lsum);
      lsum = fmaf(dz, dz, lsum); lsum = fmaf(dw, dw, lsum);
    }
    if (h == 0) out_idx[n] = (float)bi;
    float s = lsum;
#pragma unroll
    for (int off = 32; off > 0; off >>= 1) s += __shfl_xor(s, off, 64);
    if (l == 0) wsm[w] = s;
  }
  __syncthreads();
  if (t == 0) block_loss[blockIdx.x] = ((wsm[0] + wsm[1]) + wsm[2]) + wsm[3];
}

// ---- finalize loss (deterministic tree) ------------------------------------
__global__ __launch_bounds__(256) void loss_finalize(
    const float* __restrict__ bl, float* __restrict__ out_loss) {
  __shared__ float sm[256];
  const int t = threadIdx.x;
  float s = 0.f;
  for (int i = t; i < NBLK_A; i += 256) s += bl[i];
  sm[t] = s;
  __syncthreads();
#pragma unroll
  for (int off = 128; off > 0; off >>= 1) {
    if (t < off) sm[t] += sm[t + off];
    __syncthreads();
  }
  if (t == 0) out_loss[0] = sm[0] * (1.0f / 16777216.0f);  // /(N*D)
}

extern "C" void kernel_launch(void* const* d_in, const int* in_sizes, int n_in,
                              void* d_out, int out_size, void* d_ws, size_t ws_size,
                              hipStream_t stream) {
  const float* z_e = (const float*)d_in[0];
  const float* emb = (const float*)d_in[1];

  float* out      = (float*)d_out;
  float* out_zq   = out;                          // N*D
  float* out_idx  = out + (size_t)N_TOK * D;      // N
  float* out_loss = out_idx + N_TOK;              // 1

  char* wsb = (char*)d_ws;
  float*          esqp = (float*)(wsb + WS_ESQ);
  float*          bl   = (float*)(wsb + WS_BL);
  unsigned short* ef   = (unsigned short*)(wsb + WS_EFRAG);

  prep_kernel<<<64, 512, 0, stream>>>(emb, ef, esqp);
  vq_mfma<<<NBLK_A, 256, 0, stream>>>(z_e, emb, ef, esqp, out_zq, out_idx, bl);
  loss_finalize<<<1, 256, 0, stream>>>(bl, out_loss);
}

// Round 20
// 126.253 us; speedup vs baseline: 1.8779x; 1.1014x over previous
//
#include <hip/hip_runtime.h>

// VQ codebook via MFMA: z_e (262144,64) f32, embeddings (512,64) f32.
// Outputs (flat f32): z_q_st [N*D], indices-as-float [N], loss [1].
//
// R20 = R19 with two rescan-cost cuts (no arithmetic changes):
// (1) pre-epilogue __syncthreads DELETED: sIdx[w*32+j] is written and read
//     by the SAME wave (epilogue thread 2*tk sits in wave tk/32), so only
//     within-wave LDS ordering (lgkmcnt, compiler-inserted) is needed.
//     Waves without flagged tokens no longer wait for other waves' rescans
//     (R18 lesson: the rescan's 64-way-scattered e-loads cost ~10us per
//     flagged token and the barrier amplified it 4x).
// (2) THRESH 0.02 -> 0.01: worst-case bf16-split gap error ~2.2e-3, so
//     >=4.5x margin remains; flag rate (and rescan work) halves.
// Hot loop / prep / epilogue / finalize byte-identical to R19 (absmax 0).

typedef short  bf16x8 __attribute__((ext_vector_type(8)));
typedef float  f32x4  __attribute__((ext_vector_type(4)));

static constexpr int N_TOK = 262144;
static constexpr int K     = 512;
static constexpr int D     = 64;
static constexpr float THRESH = 0.01f;
static constexpr int NBLK_A = N_TOK / 128;    // 2048 vq_mfma blocks

// ws layout (bytes)
static constexpr size_t WS_ESQ   = 0;         //  512 f32 (2048 B)
static constexpr size_t WS_BL    = 2048;      // 2048 f32 (8192 B)
static constexpr size_t WS_EFRAG = 10240;     // 65536 u16 (131072 B), 16B-al

#define GLDS16(G, L) __builtin_amdgcn_global_load_lds(                    \
    (const __attribute__((address_space(1))) void*)(G),                   \
    (__attribute__((address_space(3))) void*)(L), 16, 0, 0)

// ---- prep: E' = -2E -> bf16 hi/lo A-frags, fused with esq ------------------
__global__ __launch_bounds__(512) void prep_kernel(
    const float* __restrict__ emb, unsigned short* __restrict__ ef,
    float* __restrict__ esq) {
  int idx  = blockIdx.x * 512 + threadIdx.x;   // 32768 = 512 codes * 64 d
  int code = idx >> 6, d = idx & 63;
  float s  = -2.0f * emb[code * 64 + d];
  unsigned u  = __float_as_uint(s);
  unsigned hi = (u + 0x7FFFu + ((u >> 16) & 1u)) >> 16;       // RNE bf16
  float lof   = s - __uint_as_float(hi << 16);
  unsigned v2 = __float_as_uint(lof);
  unsigned lo = (v2 + 0x7FFFu + ((v2 >> 16) & 1u)) >> 16;     // RNE bf16
  int tile = code >> 4, row = code & 15;
  int c = (d >> 5) & 1, g = (d >> 3) & 3, i = d & 7;
  int lane = row + (g << 4);
  size_t base = ((size_t)tile * 256 + (size_t)c * 128) * 8;
  ef[base + (size_t)(0 * 64 + lane) * 8 + i] = (unsigned short)hi;
  ef[base + (size_t)(1 * 64 + lane) * 8 + i] = (unsigned short)lo;
  // esq for this block's 8 codes (rows L1-hot from the reads above).
  if (threadIdx.x < 8) {
    int k = blockIdx.x * 8 + threadIdx.x;
    const float4* row4 = reinterpret_cast<const float4*>(emb + (size_t)k * D);
    float acc = 0.f;
#pragma unroll
    for (int j = 0; j < 16; ++j) {
      float4 v = row4[j];
      acc = fmaf(v.x, v.x, acc); acc = fmaf(v.y, v.y, acc);
      acc = fmaf(v.z, v.z, acc); acc = fmaf(v.w, v.w, acc);
    }
    esq[k] = acc;
  }
}

// RNE bf16 two-term split of 8 floats -> hi/lo bf16x8.
__device__ __forceinline__ void split8(float4 a, float4 b,
                                       bf16x8& h, bf16x8& lo) {
  float v[8] = {a.x, a.y, a.z, a.w, b.x, b.y, b.z, b.w};
#pragma unroll
  for (int i = 0; i < 8; ++i) {
    unsigned u  = __float_as_uint(v[i]);
    unsigned hi = (u + 0x7FFFu + ((u >> 16) & 1u)) >> 16;
    float lof   = v[i] - __uint_as_float(hi << 16);
    unsigned v2 = __float_as_uint(lof);
    unsigned l2 = (v2 + 0x7FFFu + ((v2 >> 16) & 1u)) >> 16;
    h[i]  = (short)hi;
    lo[i] = (short)l2;
  }
}

#define ARGMIN4(C, BASE, BEST, SECOND, BIDXV)               \
  {                                                         \
    _Pragma("unroll")                                       \
    for (int r = 0; r < 4; ++r) {                           \
      float v = (C)[r];                                     \
      bool lt = v < (BEST);                                 \
      float mn = fminf((SECOND), v);                        \
      (SECOND) = lt ? (BEST) : mn;                          \
      (BIDXV)  = lt ? ((BASE) + r) : (BIDXV);               \
      (BEST)   = lt ? v : (BEST);                           \
    }                                                       \
  }

// ---- kernel A: MFMA distances + inline rescan + fused epilogue -------------
__global__ __launch_bounds__(256) void vq_mfma(
    const float* __restrict__ z_e, const float* __restrict__ emb,
    const unsigned short* __restrict__ efrag, const float* __restrict__ esq_g,
    float* __restrict__ out_zq, float* __restrict__ out_idx,
    float* __restrict__ block_loss) {
  __shared__ float esql[K];                        // 2048 B
  __shared__ __align__(16) short lds_eb[2][4096];  // 2 x 8KB (tile-pair dbuf)
  __shared__ int   sIdx[128];
  __shared__ float wsm[4];

  const int t  = threadIdx.x;
  const int l  = t & 63;
  const int w  = t >> 6;
  const int wu = __builtin_amdgcn_readfirstlane(w);  // SGPR wave id
  const int g  = l >> 4, g4 = g << 2;
  const int gtok0 = blockIdx.x * 128;

  esql[t] = esq_g[t];
  esql[t + 256] = esq_g[t + 256];

  // z frags for two token rows, direct from global. RNE split = efrag's.
  bf16x8 zh0A, zl0A, zh1A, zl1A, zh0B, zl0B, zh1B, zl1B;
  {
    const int rowA = gtok0 + w * 32 + (l & 15);
    const float* zp = z_e + (size_t)rowA * D + g * 8;
    float4 q0 = *reinterpret_cast<const float4*>(zp);
    float4 q1 = *reinterpret_cast<const float4*>(zp + 4);
    float4 q2 = *reinterpret_cast<const float4*>(zp + 32);
    float4 q3 = *reinterpret_cast<const float4*>(zp + 36);
    split8(q0, q1, zh0A, zl0A);
    split8(q2, q3, zh1A, zl1A);
    zp += (size_t)16 * D;                          // rowB = rowA + 16
    q0 = *reinterpret_cast<const float4*>(zp);
    q1 = *reinterpret_cast<const float4*>(zp + 4);
    q2 = *reinterpret_cast<const float4*>(zp + 32);
    q3 = *reinterpret_cast<const float4*>(zp + 36);
    split8(q0, q1, zh0B, zl0B);
    split8(q2, q3, zh1B, zl1B);
  }

  const bf16x8* EF = reinterpret_cast<const bf16x8*>(efrag);
  // Prologue: 2-deep prefetch (pairs 0 and 1 into buf0/buf1).
  GLDS16(EF + t,        &lds_eb[0][wu * 512]);
  GLDS16(EF + 256 + t,  &lds_eb[0][2048 + wu * 512]);
  GLDS16(EF + 512 + t,  &lds_eb[1][wu * 512]);
  GLDS16(EF + 768 + t,  &lds_eb[1][2048 + wu * 512]);
  asm volatile("s_waitcnt vmcnt(2)" ::: "memory");  // pair0 landed
  __builtin_amdgcn_s_barrier();                     // + esql visible
  __builtin_amdgcn_sched_barrier(0);

  float bestA = 3.402823466e38f, secondA = 3.402823466e38f;
  float bestB = 3.402823466e38f, secondB = 3.402823466e38f;
  int idxA = 0, idxB = 0;

  for (int it = 0; it < 16; ++it) {
    const bf16x8* eb = reinterpret_cast<const bf16x8*>(&lds_eb[it & 1][0]);

#pragma unroll
    for (int half = 0; half < 2; ++half) {
      const int tile = 2 * it + half;
      const bf16x8* tb = eb + half * 256;
      f32x4 CA = *reinterpret_cast<const f32x4*>(&esql[tile * 16 + g4]);
      f32x4 CB = CA;
      bf16x8 e0h = tb[l], e0l = tb[64 + l];
      bf16x8 e1h = tb[128 + l], e1l = tb[192 + l];
      __builtin_amdgcn_s_setprio(1);
      CA = __builtin_amdgcn_mfma_f32_16x16x32_bf16(e0h, zh0A, CA, 0, 0, 0);
      CB = __builtin_amdgcn_mfma_f32_16x16x32_bf16(e0h, zh0B, CB, 0, 0, 0);
      CA = __builtin_amdgcn_mfma_f32_16x16x32_bf16(e0h, zl0A, CA, 0, 0, 0);
      CB = __builtin_amdgcn_mfma_f32_16x16x32_bf16(e0h, zl0B, CB, 0, 0, 0);
      CA = __builtin_amdgcn_mfma_f32_16x16x32_bf16(e0l, zh0A, CA, 0, 0, 0);
      CB = __builtin_amdgcn_mfma_f32_16x16x32_bf16(e0l, zh0B, CB, 0, 0, 0);
      CA = __builtin_amdgcn_mfma_f32_16x16x32_bf16(e1h, zh1A, CA, 0, 0, 0);
      CB = __builtin_amdgcn_mfma_f32_16x16x32_bf16(e1h, zh1B, CB, 0, 0, 0);
      CA = __builtin_amdgcn_mfma_f32_16x16x32_bf16(e1h, zl1A, CA, 0, 0, 0);
      CB = __builtin_amdgcn_mfma_f32_16x16x32_bf16(e1h, zl1B, CB, 0, 0, 0);
      CA = __builtin_amdgcn_mfma_f32_16x16x32_bf16(e1l, zh1A, CA, 0, 0, 0);
      CB = __builtin_amdgcn_mfma_f32_16x16x32_bf16(e1l, zh1B, CB, 0, 0, 0);
      __builtin_amdgcn_s_setprio(0);

      const int base = tile * 16 + g4;             // ascending code order
      ARGMIN4(CA, base, bestA, secondA, idxA)
      ARGMIN4(CB, base, bestB, secondB, idxB)
    }

    // Counted-vmcnt buffer rotation (no full drain in steady state).
    __builtin_amdgcn_sched_barrier(0);
    __builtin_amdgcn_s_barrier();                  // all waves done reading buf
    if (it < 14) {
      const bf16x8* src = EF + (size_t)(it + 2) * 512;
      GLDS16(src + t,       &lds_eb[it & 1][wu * 512]);        // reuse buf
      GLDS16(src + 256 + t, &lds_eb[it & 1][2048 + wu * 512]);
      asm volatile("s_waitcnt vmcnt(2)" ::: "memory");  // pair(it+1) landed
    } else if (it == 14) {
      asm volatile("s_waitcnt vmcnt(0)" ::: "memory");  // pair15 landed
    }
    __builtin_amdgcn_s_barrier();                  // landed for ALL waves
    __builtin_amdgcn_sched_barrier(0);
  }

  // Reduce each group across lanes {l, l^16, l^32, l^48}; ties -> smaller code.
#pragma unroll
  for (int mask = 16; mask <= 32; mask <<= 1) {
    float ob, os; int oi; bool take; float hi2;
    ob = __shfl_xor(bestA, mask); oi = __shfl_xor(idxA, mask);
    os = __shfl_xor(secondA, mask);
    hi2 = fmaxf(bestA, ob);
    secondA = fminf(secondA, fminf(os, hi2));
    take = (ob < bestA) || (ob == bestA && oi < idxA);
    bestA = take ? ob : bestA; idxA = take ? oi : idxA;

    ob = __shfl_xor(bestB, mask); oi = __shfl_xor(idxB, mask);
    os = __shfl_xor(secondB, mask);
    hi2 = fmaxf(bestB, ob);
    secondB = fminf(secondB, fminf(os, hi2));
    take = (ob < bestB) || (ob == bestB && oi < idxB);
    bestB = take ? ob : bestB; idxB = take ? oi : idxB;
  }

  if (l < 16) {
    sIdx[w * 32 + l]      = idxA;
    sIdx[w * 32 + 16 + l] = idxB;
  }

  // Inline exact rescan of flagged tokens (wave-uniform ballot loop).
  // Register-light: two acc[4] passes, unroll-1 d-loop. Same-wave tokens
  // only -> no cross-wave barrier needed before the epilogue.
  {
    bool fA = (l < 16) && ((secondA - bestA) < THRESH);
    bool fB = (l < 16) && ((secondB - bestB) < THRESH);
    unsigned long long ba = __ballot(fA);
    unsigned long long bb = __ballot(fB);
    unsigned mask = (unsigned)((ba & 0xFFFFull) | ((bb & 0xFFFFull) << 16));
    while (mask) {
      const int j = __builtin_ctz(mask);
      mask &= mask - 1;
      const int n = gtok0 + w * 32 + j;
      const float4* zr = reinterpret_cast<const float4*>(z_e + (size_t)n * D);
      float best = 3.402823466e38f; int bid = 0;
#pragma unroll 1
      for (int half2 = 0; half2 < 2; ++half2) {
        float acc[4];
#pragma unroll
        for (int m = 0; m < 4; ++m) acc[m] = 0.f;
#pragma unroll 1
        for (int i = 0; i < 16; ++i) {
          float4 z4 = zr[i];                       // uniform addr broadcast
#pragma unroll
          for (int m = 0; m < 4; ++m) {
            const float4 e4 = *reinterpret_cast<const float4*>(
                emb + (size_t)(l + 64 * (half2 * 4 + m)) * D + 4 * i);
            acc[m] = fmaf(z4.x, e4.x, acc[m]);
            acc[m] = fmaf(z4.y, e4.y, acc[m]);
            acc[m] = fmaf(z4.z, e4.z, acc[m]);
            acc[m] = fmaf(z4.w, e4.w, acc[m]);
          }
        }
#pragma unroll
        for (int m = 0; m < 4; ++m) {
          const int code = l + 64 * (half2 * 4 + m);
          float s = fmaf(-2.f, acc[m], esq_g[code]);
          if (s < best) { best = s; bid = code; }  // ascending overall
        }
      }
#pragma unroll
      for (int mk = 1; mk <= 32; mk <<= 1) {       // lexicographic min
        float ob = __shfl_xor(best, mk);
        int   oi = __shfl_xor(bid, mk);
        bool take = (ob < best) || (ob == best && oi < bid);
        best = take ? ob : best;
        bid  = take ? oi : bid;
      }
      if (l == 0) sIdx[w * 32 + j] = bid;          // patch (same-wave read)
    }
  }
  // NO __syncthreads here: sIdx[w*32..w*32+32) is produced and consumed by
  // wave w only; within-wave LDS ordering is guaranteed via lgkmcnt.

  // Fused epilogue: 2 threads/token; gather + z_q_st + idx + loss.
  {
    const int tk = t >> 1, h = t & 1;
    const int n = gtok0 + tk;
    const int bi = sIdx[tk];
    const float4* er = reinterpret_cast<const float4*>(emb + (size_t)bi * D);
    const float4* zr = reinterpret_cast<const float4*>(z_e + (size_t)n * D);
    float4* orow = reinterpret_cast<float4*>(out_zq + (size_t)n * D);
    float lsum = 0.f;
#pragma unroll
    for (int j = 0; j < 8; ++j) {
      int i = h * 8 + j;
      float4 Q = er[i], Z = zr[i];
      float dx = Q.x - Z.x, dy = Q.y - Z.y, dz = Q.z - Z.z, dw = Q.w - Z.w;
      float4 st;
      st.x = Z.x + dx; st.y = Z.y + dy; st.z = Z.z + dz; st.w = Z.w + dw;
      orow[i] = st;
      lsum = fmaf(dx, dx, lsum); lsum = fmaf(dy, dy, lsum);
      lsum = fmaf(dz, dz, lsum); lsum = fmaf(dw, dw, lsum);
    }
    if (h == 0) out_idx[n] = (float)bi;
    float s = lsum;
#pragma unroll
    for (int off = 32; off > 0; off >>= 1) s += __shfl_xor(s, off, 64);
    if (l == 0) wsm[w] = s;
  }
  __syncthreads();
  if (t == 0) block_loss[blockIdx.x] = ((wsm[0] + wsm[1]) + wsm[2]) + wsm[3];
}

// ---- finalize loss (deterministic tree) ------------------------------------
__global__ __launch_bounds__(256) void loss_finalize(
    const float* __restrict__ bl, float* __restrict__ out_loss) {
  __shared__ float sm[256];
  const int t = threadIdx.x;
  float s = 0.f;
  for (int i = t; i < NBLK_A; i += 256) s += bl[i];
  sm[t] = s;
  __syncthreads();
#pragma unroll
  for (int off = 128; off > 0; off >>= 1) {
    if (t < off) sm[t] += sm[t + off];
    __syncthreads();
  }
  if (t == 0) out_loss[0] = sm[0] * (1.0f / 16777216.0f);  // /(N*D)
}

extern "C" void kernel_launch(void* const* d_in, const int* in_sizes, int n_in,
                              void* d_out, int out_size, void* d_ws, size_t ws_size,
                              hipStream_t stream) {
  const float* z_e = (const float*)d_in[0];
  const float* emb = (const float*)d_in[1];

  float* out      = (float*)d_out;
  float* out_zq   = out;                          // N*D
  float* out_idx  = out + (size_t)N_TOK * D;      // N
  float* out_loss = out_idx + N_TOK;              // 1

  char* wsb = (char*)d_ws;
  float*          esqp = (float*)(wsb + WS_ESQ);
  float*          bl   = (float*)(wsb + WS_BL);
  unsigned short* ef   = (unsigned short*)(wsb + WS_EFRAG);

  prep_kernel<<<64, 512, 0, stream>>>(emb, ef, esqp);
  vq_mfma<<<NBLK_A, 256, 0, stream>>>(z_e, emb, ef, esqp, out_zq, out_idx, bl);
  loss_finalize<<<1, 256, 0, stream>>>(bl, out_loss);
}

// Round 21
// 104.023 us; speedup vs baseline: 2.2792x; 1.2137x over previous
//
#include <hip/hip_runtime.h>

// VQ codebook via MFMA: z_e (262144,64) f32, embeddings (512,64) f32.
// Outputs (flat f32): z_q_st [N*D], indices-as-float [N], loss [1].
//
// R21: PERSISTENT codebook. All 32 E-tile fragments (128KB hi+lo) staged to
// LDS ONCE; grid = 256 blocks (1/CU) x 1024 threads (16 waves). Main loop
// has ZERO barriers / ZERO restaging: each wave independently does 2 passes
// x 32 tokens x 32 tiles (ds_read + 12 MFMA + argmin). Residency is
// LDS-pinned at 16 waves/CU -- immune to the allocator (R1-R17 lesson).
// R20 post-mortem: no pipe >32% busy; per-iter barrier lockstep + 1MB/CU
// E-restaging starved the CU. Per-token MFMA order / argmin / ballot rescan
// / epilogue bitwise = R20 (absmax 0 x9 rounds); only index bases changed.

typedef short  bf16x8 __attribute__((ext_vector_type(8)));
typedef float  f32x4  __attribute__((ext_vector_type(4)));

static constexpr int N_TOK = 262144;
static constexpr int K     = 512;
static constexpr int D     = 64;
static constexpr float THRESH = 0.01f;
static constexpr int NBLK_A = N_TOK / 1024;   // 256 blocks (1 per CU)

// ws layout (bytes)
static constexpr size_t WS_ESQ   = 0;         //  512 f32 (2048 B)
static constexpr size_t WS_BL    = 2048;      //  256 f32 (1024 B)
static constexpr size_t WS_EFRAG = 10240;     // 65536 u16 (131072 B), 16B-al

#define GLDS16(G, L) __builtin_amdgcn_global_load_lds(                    \
    (const __attribute__((address_space(1))) void*)(G),                   \
    (__attribute__((address_space(3))) void*)(L), 16, 0, 0)

// ---- prep: E' = -2E -> bf16 hi/lo A-frags, fused with esq ------------------
__global__ __launch_bounds__(512) void prep_kernel(
    const float* __restrict__ emb, unsigned short* __restrict__ ef,
    float* __restrict__ esq) {
  int idx  = blockIdx.x * 512 + threadIdx.x;   // 32768 = 512 codes * 64 d
  int code = idx >> 6, d = idx & 63;
  float s  = -2.0f * emb[code * 64 + d];
  unsigned u  = __float_as_uint(s);
  unsigned hi = (u + 0x7FFFu + ((u >> 16) & 1u)) >> 16;       // RNE bf16
  float lof   = s - __uint_as_float(hi << 16);
  unsigned v2 = __float_as_uint(lof);
  unsigned lo = (v2 + 0x7FFFu + ((v2 >> 16) & 1u)) >> 16;     // RNE bf16
  int tile = code >> 4, row = code & 15;
  int c = (d >> 5) & 1, g = (d >> 3) & 3, i = d & 7;
  int lane = row + (g << 4);
  size_t base = ((size_t)tile * 256 + (size_t)c * 128) * 8;
  ef[base + (size_t)(0 * 64 + lane) * 8 + i] = (unsigned short)hi;
  ef[base + (size_t)(1 * 64 + lane) * 8 + i] = (unsigned short)lo;
  // esq for this block's 8 codes (rows L1-hot from the reads above).
  if (threadIdx.x < 8) {
    int k = blockIdx.x * 8 + threadIdx.x;
    const float4* row4 = reinterpret_cast<const float4*>(emb + (size_t)k * D);
    float acc = 0.f;
#pragma unroll
    for (int j = 0; j < 16; ++j) {
      float4 v = row4[j];
      acc = fmaf(v.x, v.x, acc); acc = fmaf(v.y, v.y, acc);
      acc = fmaf(v.z, v.z, acc); acc = fmaf(v.w, v.w, acc);
    }
    esq[k] = acc;
  }
}

// RNE bf16 two-term split of 8 floats -> hi/lo bf16x8.
__device__ __forceinline__ void split8(float4 a, float4 b,
                                       bf16x8& h, bf16x8& lo) {
  float v[8] = {a.x, a.y, a.z, a.w, b.x, b.y, b.z, b.w};
#pragma unroll
  for (int i = 0; i < 8; ++i) {
    unsigned u  = __float_as_uint(v[i]);
    unsigned hi = (u + 0x7FFFu + ((u >> 16) & 1u)) >> 16;
    float lof   = v[i] - __uint_as_float(hi << 16);
    unsigned v2 = __float_as_uint(lof);
    unsigned l2 = (v2 + 0x7FFFu + ((v2 >> 16) & 1u)) >> 16;
    h[i]  = (short)hi;
    lo[i] = (short)l2;
  }
}

#define ARGMIN4(C, BASE, BEST, SECOND, BIDXV)               \
  {                                                         \
    _Pragma("unroll")                                       \
    for (int r = 0; r < 4; ++r) {                           \
      float v = (C)[r];                                     \
      bool lt = v < (BEST);                                 \
      float mn = fminf((SECOND), v);                        \
      (SECOND) = lt ? (BEST) : mn;                          \
      (BIDXV)  = lt ? ((BASE) + r) : (BIDXV);               \
      (BEST)   = lt ? v : (BEST);                           \
    }                                                       \
  }

// ---- kernel A: persistent-codebook MFMA + rescan + fused epilogue ----------
__global__ __launch_bounds__(1024) void vq_mfma(
    const float* __restrict__ z_e, const float* __restrict__ emb,
    const unsigned short* __restrict__ efrag, const float* __restrict__ esq_g,
    float* __restrict__ out_zq, float* __restrict__ out_idx,
    float* __restrict__ block_loss) {
  __shared__ float esql[K];                         // 2 KB
  __shared__ __align__(16) short lds_e[65536];      // 128 KB: all 32 tiles
  __shared__ int   sIdx[512];                       // 2 KB (per-wave slices)
  __shared__ float wsm[16];

  const int t  = threadIdx.x;                       // 0..1023
  const int l  = t & 63;
  const int wu = __builtin_amdgcn_readfirstlane(t >> 6);  // wave 0..15
  const int g  = l >> 4, g4 = g << 2;
  const int blk0 = blockIdx.x * 1024;               // this block's tokens

  if (t < K) esql[t] = esq_g[t];

  const bf16x8* EF = reinterpret_cast<const bf16x8*>(efrag);
  // Stage the whole codebook frag array: 8 rounds x 16KB (1024 thr x 16B).
#pragma unroll
  for (int r = 0; r < 8; ++r)
    GLDS16(EF + r * 1024 + t, &lds_e[r * 8192 + wu * 512]);
  asm volatile("s_waitcnt vmcnt(0)" ::: "memory");
  __builtin_amdgcn_s_barrier();                     // one-time; none after

  float blsum = 0.f;

  for (int pass = 0; pass < 2; ++pass) {
    const int tok0 = blk0 + pass * 512 + wu * 32;   // wave's 32 tokens

    // z frags for rows tok0+(l&15) [A] and +16 [B]. RNE split = efrag's.
    bf16x8 zh0A, zl0A, zh1A, zl1A, zh0B, zl0B, zh1B, zl1B;
    {
      const int rowA = tok0 + (l & 15);
      const float* zp = z_e + (size_t)rowA * D + g * 8;
      float4 q0 = *reinterpret_cast<const float4*>(zp);
      float4 q1 = *reinterpret_cast<const float4*>(zp + 4);
      float4 q2 = *reinterpret_cast<const float4*>(zp + 32);
      float4 q3 = *reinterpret_cast<const float4*>(zp + 36);
      split8(q0, q1, zh0A, zl0A);
      split8(q2, q3, zh1A, zl1A);
      zp += (size_t)16 * D;                         // rowB = rowA + 16
      q0 = *reinterpret_cast<const float4*>(zp);
      q1 = *reinterpret_cast<const float4*>(zp + 4);
      q2 = *reinterpret_cast<const float4*>(zp + 32);
      q3 = *reinterpret_cast<const float4*>(zp + 36);
      split8(q0, q1, zh0B, zl0B);
      split8(q2, q3, zh1B, zl1B);
    }

    float bestA = 3.402823466e38f, secondA = 3.402823466e38f;
    float bestB = 3.402823466e38f, secondB = 3.402823466e38f;
    int idxA = 0, idxB = 0;

    for (int tile = 0; tile < 32; ++tile) {         // ascending code order
      const bf16x8* tb =
          reinterpret_cast<const bf16x8*>(&lds_e[(size_t)tile * 2048]);
      f32x4 CA = *reinterpret_cast<const f32x4*>(&esql[tile * 16 + g4]);
      f32x4 CB = CA;
      bf16x8 e0h = tb[l], e0l = tb[64 + l];
      bf16x8 e1h = tb[128 + l], e1l = tb[192 + l];
      __builtin_amdgcn_s_setprio(1);
      CA = __builtin_amdgcn_mfma_f32_16x16x32_bf16(e0h, zh0A, CA, 0, 0, 0);
      CB = __builtin_amdgcn_mfma_f32_16x16x32_bf16(e0h, zh0B, CB, 0, 0, 0);
      CA = __builtin_amdgcn_mfma_f32_16x16x32_bf16(e0h, zl0A, CA, 0, 0, 0);
      CB = __builtin_amdgcn_mfma_f32_16x16x32_bf16(e0h, zl0B, CB, 0, 0, 0);
      CA = __builtin_amdgcn_mfma_f32_16x16x32_bf16(e0l, zh0A, CA, 0, 0, 0);
      CB = __builtin_amdgcn_mfma_f32_16x16x32_bf16(e0l, zh0B, CB, 0, 0, 0);
      CA = __builtin_amdgcn_mfma_f32_16x16x32_bf16(e1h, zh1A, CA, 0, 0, 0);
      CB = __builtin_amdgcn_mfma_f32_16x16x32_bf16(e1h, zh1B, CB, 0, 0, 0);
      CA = __builtin_amdgcn_mfma_f32_16x16x32_bf16(e1h, zl1A, CA, 0, 0, 0);
      CB = __builtin_amdgcn_mfma_f32_16x16x32_bf16(e1h, zl1B, CB, 0, 0, 0);
      CA = __builtin_amdgcn_mfma_f32_16x16x32_bf16(e1l, zh1A, CA, 0, 0, 0);
      CB = __builtin_amdgcn_mfma_f32_16x16x32_bf16(e1l, zh1B, CB, 0, 0, 0);
      __builtin_amdgcn_s_setprio(0);

      const int base = tile * 16 + g4;
      ARGMIN4(CA, base, bestA, secondA, idxA)
      ARGMIN4(CB, base, bestB, secondB, idxB)
    }

    // Reduce across lanes {l, l^16, l^32, l^48}; ties -> smaller code.
#pragma unroll
    for (int mask = 16; mask <= 32; mask <<= 1) {
      float ob, os; int oi; bool take; float hi2;
      ob = __shfl_xor(bestA, mask); oi = __shfl_xor(idxA, mask);
      os = __shfl_xor(secondA, mask);
      hi2 = fmaxf(bestA, ob);
      secondA = fminf(secondA, fminf(os, hi2));
      take = (ob < bestA) || (ob == bestA && oi < idxA);
      bestA = take ? ob : bestA; idxA = take ? oi : idxA;

      ob = __shfl_xor(bestB, mask); oi = __shfl_xor(idxB, mask);
      os = __shfl_xor(secondB, mask);
      hi2 = fmaxf(bestB, ob);
      secondB = fminf(secondB, fminf(os, hi2));
      take = (ob < bestB) || (ob == bestB && oi < idxB);
      bestB = take ? ob : bestB; idxB = take ? oi : idxB;
    }

    if (l < 16) {
      sIdx[wu * 32 + l]      = idxA;
      sIdx[wu * 32 + 16 + l] = idxB;
    }

    // Inline exact rescan of flagged tokens (same-wave ballot loop).
    {
      bool fA = (l < 16) && ((secondA - bestA) < THRESH);
      bool fB = (l < 16) && ((secondB - bestB) < THRESH);
      unsigned long long ba = __ballot(fA);
      unsigned long long bb = __ballot(fB);
      unsigned mask = (unsigned)((ba & 0xFFFFull) | ((bb & 0xFFFFull) << 16));
      while (mask) {
        const int j = __builtin_ctz(mask);
        mask &= mask - 1;
        const int n = tok0 + j;
        const float4* zr =
            reinterpret_cast<const float4*>(z_e + (size_t)n * D);
        float best = 3.402823466e38f; int bid = 0;
#pragma unroll 1
        for (int half2 = 0; half2 < 2; ++half2) {
          float acc[4];
#pragma unroll
          for (int m = 0; m < 4; ++m) acc[m] = 0.f;
#pragma unroll 1
          for (int i = 0; i < 16; ++i) {
            float4 z4 = zr[i];                     // uniform addr broadcast
#pragma unroll
            for (int m = 0; m < 4; ++m) {
              const float4 e4 = *reinterpret_cast<const float4*>(
                  emb + (size_t)(l + 64 * (half2 * 4 + m)) * D + 4 * i);
              acc[m] = fmaf(z4.x, e4.x, acc[m]);
              acc[m] = fmaf(z4.y, e4.y, acc[m]);
              acc[m] = fmaf(z4.z, e4.z, acc[m]);
              acc[m] = fmaf(z4.w, e4.w, acc[m]);
            }
          }
#pragma unroll
          for (int m = 0; m < 4; ++m) {
            const int code = l + 64 * (half2 * 4 + m);
            float s = fmaf(-2.f, acc[m], esq_g[code]);
            if (s < best) { best = s; bid = code; }
          }
        }
#pragma unroll
        for (int mk = 1; mk <= 32; mk <<= 1) {     // lexicographic min
          float ob = __shfl_xor(best, mk);
          int   oi = __shfl_xor(bid, mk);
          bool take = (ob < best) || (ob == best && oi < bid);
          best = take ? ob : best;
          bid  = take ? oi : bid;
        }
        if (l == 0) sIdx[wu * 32 + j] = bid;       // same-wave patch
      }
    }
    // No barrier: sIdx[wu*32..+32) produced and consumed by wave wu only.

    // Fused epilogue: 2 lanes/token within the wave.
    {
      const int tk = l >> 1, h = l & 1;
      const int n = tok0 + tk;
      const int bi = sIdx[wu * 32 + tk];
      const float4* er =
          reinterpret_cast<const float4*>(emb + (size_t)bi * D);
      const float4* zr =
          reinterpret_cast<const float4*>(z_e + (size_t)n * D);
      float4* orow = reinterpret_cast<float4*>(out_zq + (size_t)n * D);
      float lsum = 0.f;
#pragma unroll
      for (int j = 0; j < 8; ++j) {
        int i = h * 8 + j;
        float4 Q = er[i], Z = zr[i];
        float dx = Q.x - Z.x, dy = Q.y - Z.y, dz = Q.z - Z.z, dw = Q.w - Z.w;
        float4 st;
        st.x = Z.x + dx; st.y = Z.y + dy; st.z = Z.z + dz; st.w = Z.w + dw;
        orow[i] = st;
        lsum = fmaf(dx, dx, lsum); lsum = fmaf(dy, dy, lsum);
        lsum = fmaf(dz, dz, lsum); lsum = fmaf(dw, dw, lsum);
      }
      if (h == 0) out_idx[n] = (float)bi;
      float s = lsum;
#pragma unroll
      for (int off = 32; off > 0; off >>= 1) s += __shfl_xor(s, off, 64);
      blsum += s;                                  // uniform across lanes
    }
  }

  if (l == 0) wsm[wu] = blsum;
  __syncthreads();
  if (t == 0) {
    float s = 0.f;
#pragma unroll
    for (int i = 0; i < 16; ++i) s += wsm[i];      // fixed ascending order
    block_loss[blockIdx.x] = s;
  }
}

// ---- finalize loss (deterministic tree, 256 partials) ----------------------
__global__ __launch_bounds__(256) void loss_finalize(
    const float* __restrict__ bl, float* __restrict__ out_loss) {
  __shared__ float sm[256];
  const int t = threadIdx.x;
  sm[t] = bl[t];
  __syncthreads();
#pragma unroll
  for (int off = 128; off > 0; off >>= 1) {
    if (t < off) sm[t] += sm[t + off];
    __syncthreads();
  }
  if (t == 0) out_loss[0] = sm[0] * (1.0f / 16777216.0f);  // /(N*D)
}

extern "C" void kernel_launch(void* const* d_in, const int* in_sizes, int n_in,
                              void* d_out, int out_size, void* d_ws, size_t ws_size,
                              hipStream_t stream) {
  const float* z_e = (const float*)d_in[0];
  const float* emb = (const float*)d_in[1];

  float* out      = (float*)d_out;
  float* out_zq   = out;                          // N*D
  float* out_idx  = out + (size_t)N_TOK * D;      // N
  float* out_loss = out_idx + N_TOK;              // 1

  char* wsb = (char*)d_ws;
  float*          esqp = (float*)(wsb + WS_ESQ);
  float*          bl   = (float*)(wsb + WS_BL);
  unsigned short* ef   = (unsigned short*)(wsb + WS_EFRAG);

  prep_kernel<<<64, 512, 0, stream>>>(emb, ef, esqp);
  vq_mfma<<<NBLK_A, 1024, 0, stream>>>(z_e, emb, ef, esqp, out_zq, out_idx, bl);
  loss_finalize<<<1, 256, 0, stream>>>(bl, out_loss);
}